// Round 2
// baseline (32.054 us; speedup 1.0000x reference)
//
#include <hip/hip_runtime.h>

#define NB    32
#define NT    8192
#define NF    128
#define NOUT  1024
#define SEGSZ 32
#define NSEG  256          // NT / SEGSZ
#define TILE  32           // outputs per phase-2 block
#define NTILE (NOUT/TILE)  // 32 tiles per batch

__device__ __forceinline__ float4 f4add(float4 a, float4 b) {
  return make_float4(a.x + b.x, a.y + b.y, a.z + b.z, a.w + b.w);
}
__device__ __forceinline__ float4 f4sub(float4 a, float4 b) {
  return make_float4(a.x - b.x, a.y - b.y, a.z - b.z, a.w - b.w);
}

// Phase 1: one block per (b, group of 128 rows) -> 4 segment sums of 32 rows.
__global__ __launch_bounds__(256) void seg_sums(const float* __restrict__ x,
                                                const int* __restrict__ lengths,
                                                float* __restrict__ S) {
  const int blk = blockIdx.x;       // b * 64 + g
  const int b   = blk >> 6;
  const int g   = blk & 63;         // 128-row group
  const int len = lengths[b];
  if (g * 128 >= len) return;       // rows never consumed

  const int tid = threadIdx.x;
  const int f4  = tid & 31;
  const int tl  = tid >> 5;         // 0..7, rows [16*tl, 16*tl+16)

  const float4* xp =
      reinterpret_cast<const float4*>(x + (size_t)b * NT * NF +
                                      (size_t)(g * 128) * NF) + f4;
  float4 acc = make_float4(0.f, 0.f, 0.f, 0.f);
  #pragma unroll
  for (int r = 0; r < 16; ++r)
    acc = f4add(acc, xp[(tl * 16 + r) * 32]);

  __shared__ float4 red[8][32];
  red[tl][f4] = acc;
  __syncthreads();
  if (tl < 4) {                     // segment tl of this group (32 rows each)
    float4 s = f4add(red[2 * tl][f4], red[2 * tl + 1][f4]);
    reinterpret_cast<float4*>(S + ((size_t)b * NSEG + g * 4 + tl) * NF)[f4] = s;
  }
}

// Phase 2: one block per (b, 32-output tile); 8 t-lanes x 32 f4-lanes,
// each t-lane owns 4 consecutive outputs and slides the window.
__global__ __launch_bounds__(256) void window_avg(const float* __restrict__ x,
                                                  const int* __restrict__ lengths,
                                                  const float* __restrict__ S,
                                                  float* __restrict__ out) {
  // XCD-aware bijective swizzle: grid=1024, 8 XCDs -> 128 contiguous tasks/XCD
  const int wg   = ((blockIdx.x & 7) << 7) + (blockIdx.x >> 3);
  const int b    = wg >> 5;         // NTILE = 32
  const int tile = wg & (NTILE - 1);
  const int len  = lengths[b];
  const int W    = len - NOUT + 1;  // in [2, 7169]
  const int t0   = tile * TILE;     // multiple of SEGSZ
  const int p1   = t0 + W;
  const int s_hi = p1 >> 5;         // full segments are [tile, s_hi)

  const int tid = threadIdx.x;
  const int f4  = tid & 31;
  const int tl  = tid >> 5;         // 0..7, owns outputs t0+4*tl .. +3

  const float4* xb =
      reinterpret_cast<const float4*>(x + (size_t)b * NT * NF) + f4;
  const float4* Sb =
      reinterpret_cast<const float4*>(S + (size_t)b * NSEG * NF) + f4;

  // Cooperative A0 = cs[p1] - cs[t0]
  float4 acc = make_float4(0.f, 0.f, 0.f, 0.f);
  for (int s = tile + tl; s < s_hi; s += 8)        // full 32-row segments
    acc = f4add(acc, Sb[s * 32]);
  for (int j = (s_hi << 5) + tl; j < p1; j += 8)   // remainder rows (<32)
    acc = f4add(acc, xb[j * 32]);

  __shared__ float4 red[8][32];
  red[tl][f4] = acc;
  __syncthreads();
  float4 A = make_float4(0.f, 0.f, 0.f, 0.f);
  #pragma unroll
  for (int k = 0; k < 8; ++k) A = f4add(A, red[k][f4]);
  __syncthreads();

  // Per-lane deltas D[tl] = A(t0+4(tl+1)) - A(t0+4tl); lane 7's unused
  // (and would read x[.., >=8189..8192] unnecessarily).
  float4 D = make_float4(0.f, 0.f, 0.f, 0.f);
  if (tl < 7) {
    const int baseLo = t0 + 4 * tl;
    const int baseHi = p1 + 4 * tl;
    #pragma unroll
    for (int j = 0; j < 4; ++j) {
      float4 h = xb[(baseHi + j) * 32];
      float4 l = xb[(baseLo + j) * 32];
      D = f4add(D, f4sub(h, l));
    }
  }
  red[tl][f4] = D;
  __syncthreads();
  #pragma unroll
  for (int k = 0; k < 7; ++k)
    if (k < tl) A = f4add(A, red[k][f4]);   // exclusive prefix -> A(t0+4*tl)

  const float invW  = 1.0f / (float)W;
  const int   tbase = t0 + 4 * tl;
  float4* ob =
      reinterpret_cast<float4*>(out + ((size_t)b * NOUT + tbase) * NF) + f4;

  #pragma unroll
  for (int i = 0; i < 4; ++i) {
    ob[i * 32] = make_float4(A.x * invW, A.y * invW, A.z * invW, A.w * invW);
    if (i < 3) {                            // last update dead; max idx 8191
      float4 h = xb[(tbase + i + W) * 32];
      float4 l = xb[(tbase + i) * 32];
      A = f4add(A, f4sub(h, l));
    }
  }
}

extern "C" void kernel_launch(void* const* d_in, const int* in_sizes, int n_in,
                              void* d_out, int out_size, void* d_ws, size_t ws_size,
                              hipStream_t stream) {
  const float* x       = (const float*)d_in[0];
  const int*   lengths = (const int*)d_in[1];
  float*       S       = (float*)d_ws;      // NB*NSEG*NF floats = 4 MB
  float*       out     = (float*)d_out;

  hipLaunchKernelGGL(seg_sums, dim3(NB * 64), dim3(256), 0, stream,
                     x, lengths, S);
  hipLaunchKernelGGL(window_avg, dim3(NB * NTILE), dim3(256), 0, stream,
                     x, lengths, S, out);
}